// Round 1
// baseline (715.690 us; speedup 1.0000x reference)
//
#include <hip/hip_runtime.h>

// B=2048, N=256, M=128
// out[b] = W^T X[b] W   (einsum "ji,bjk,kl->bil")
// Strategy: bf16 MFMA (32x32x16), fused two-stage per batch:
//   per 32-row tile p of X: U_p = X_p @ W (stage1), out += W_p^T @ U_p (stage2)
// W fragments pre-packed to d_ws by prep kernel; identical layout serves as
// stage1 B-operand and stage2 A-operand (lane&31 = non-K dim for both).

typedef __attribute__((ext_vector_type(8))) short short8;
typedef __attribute__((ext_vector_type(16))) float floatx16;

struct __align__(8)  u2 { unsigned int x, y; };
struct __align__(16) u4 { unsigned int x, y, z, w; };

__device__ __forceinline__ unsigned short f2bf(float f) {
  unsigned int u = __builtin_bit_cast(unsigned int, f);
  u += 0x7FFFu + ((u >> 16) & 1u);          // round-to-nearest-even
  return (unsigned short)(u >> 16);
}

// ---------------------------------------------------------------------------
// prep: W (256x128 f32 row-major) -> fragment-ordered bf16 in ws.
// Frag element: Wf[(((w*16)+t)*64 + l)*8 + j] = W[16t + 8*(l>>5) + j][32w + (l&31)]
//   w = wave col-block (0..3), t = k-tile (0..15), l = lane, j = 0..7
// ---------------------------------------------------------------------------
__global__ void prep_w(const float* __restrict__ W, unsigned short* __restrict__ Wf) {
  int g = blockIdx.x * 256 + threadIdx.x;   // 4096 fragments
  int l = g & 63;
  int t = (g >> 6) & 15;
  int w = g >> 10;
  int row0 = 16 * t + ((l >> 5) << 3);
  int col  = 32 * w + (l & 31);
  unsigned short tmp[8];
#pragma unroll
  for (int j = 0; j < 8; ++j) tmp[j] = f2bf(W[(row0 + j) * 128 + col]);
  u4 v;
  v.x = (unsigned)tmp[0] | ((unsigned)tmp[1] << 16);
  v.y = (unsigned)tmp[2] | ((unsigned)tmp[3] << 16);
  v.z = (unsigned)tmp[4] | ((unsigned)tmp[5] << 16);
  v.w = (unsigned)tmp[6] | ((unsigned)tmp[7] << 16);
  *(u4*)(Wf + (size_t)g * 8) = v;
}

// ---------------------------------------------------------------------------
// main kernel: one batch per block, 256 threads (4 waves)
// ---------------------------------------------------------------------------
#define XS_STRIDE 260   // 32 rows x 260 bf16 (520B rows: 8B-aligned, 2-way banks)
#define US_STRIDE 36    // 128 cols x 36 bf16 (72B cols: 8B-aligned, 2-way banks)

__global__ __launch_bounds__(256, 2) void spd_kernel(
    const float* __restrict__ X,
    const unsigned short* __restrict__ Wf,
    float* __restrict__ out)
{
  __shared__ unsigned short Xs[2][32 * XS_STRIDE];   // 2 x 16640 B
  __shared__ unsigned short Us[2][128 * US_STRIDE];  // 2 x 9216 B

  const int b      = blockIdx.x;
  const int tid    = threadIdx.x;
  const int wave   = tid >> 6;
  const int lane   = tid & 63;
  const int lane31 = lane & 31;
  const int laneHi = lane >> 5;   // 0/1

  // ---- W fragments: 16 k-tiles x 16B/lane (64 VGPRs), from L2 ----
  short8 wf[16];
  {
    const unsigned short* base = Wf + ((size_t)(wave * 16) * 64 + lane) * 8;
#pragma unroll
    for (int t = 0; t < 16; ++t)
      wf[t] = *(const short8*)(base + (size_t)t * 64 * 8);
  }

  const float* xb = X + (size_t)b * 65536;

  floatx16 oacc[4];
#pragma unroll
  for (int nt = 0; nt < 4; ++nt)
#pragma unroll
    for (int i = 0; i < 16; ++i) oacc[nt][i] = 0.0f;

  float4 xreg[8];

  // stage-in of tile p: 32x256 floats contiguous at xb + p*8192.
  // thread covers elements e = q*1024 + tid*4  (perfectly coalesced 1KB/instr)
  auto load_tile = [&](int p) {
    const float* src = xb + p * 8192 + tid * 4;
#pragma unroll
    for (int q = 0; q < 8; ++q) xreg[q] = *(const float4*)(src + q * 1024);
  };
  // e -> row rr = 4q + wave, col cc = 4*lane ; write bf16 pairs (8B)
  auto store_tile = [&](int buf) {
#pragma unroll
    for (int q = 0; q < 8; ++q) {
      float4 v = xreg[q];
      u2 pk;
      pk.x = (unsigned)f2bf(v.x) | ((unsigned)f2bf(v.y) << 16);
      pk.y = (unsigned)f2bf(v.z) | ((unsigned)f2bf(v.w) << 16);
      *(u2*)&Xs[buf][(4 * q + wave) * XS_STRIDE + 4 * lane] = pk;
    }
  };

  load_tile(0);
  store_tile(0);
  __syncthreads();

  for (int p = 0; p < 8; ++p) {
    const int buf = p & 1;
    if (p < 7) load_tile(p + 1);

    // ---- stage 1: U_p[:, 32w..32w+31] = X_p @ W[:, 32w..32w+31] ----
    floatx16 uacc;
#pragma unroll
    for (int i = 0; i < 16; ++i) uacc[i] = 0.0f;

    const unsigned short* xs = &Xs[buf][lane31 * XS_STRIDE + laneHi * 8];
#pragma unroll
    for (int t = 0; t < 16; ++t) {
      const unsigned short* ap = xs + t * 16;
      u2 a0 = *(const u2*)(ap);
      u2 a1 = *(const u2*)(ap + 4);
      u4 av; av.x = a0.x; av.y = a0.y; av.z = a1.x; av.w = a1.y;
      short8 afr = __builtin_bit_cast(short8, av);
      uacc = __builtin_amdgcn_mfma_f32_32x32x16_bf16(afr, wf[t], uacc, 0, 0, 0);
    }

    // ---- U_p -> LDS (bf16, column-major [col][j], stride 36) ----
    {
      unsigned short* up = &Us[buf][(32 * wave + lane31) * US_STRIDE + 4 * laneHi];
#pragma unroll
      for (int rg = 0; rg < 4; ++rg) {
        u2 pk;
        pk.x = (unsigned)f2bf(uacc[4 * rg + 0]) | ((unsigned)f2bf(uacc[4 * rg + 1]) << 16);
        pk.y = (unsigned)f2bf(uacc[4 * rg + 2]) | ((unsigned)f2bf(uacc[4 * rg + 3]) << 16);
        *(u2*)(up + 8 * rg) = pk;   // j base = 8*rg + 4*laneHi
      }
    }

    if (p < 7) store_tile(buf ^ 1);
    __syncthreads();

    // ---- stage 2: out[32w.., :] += W_p^T @ U_p ----
    const unsigned short* us = &Us[buf][lane31 * US_STRIDE + 8 * laneHi];
#pragma unroll
    for (int nt = 0; nt < 4; ++nt) {
      const unsigned short* bp = us + nt * 32 * US_STRIDE;
#pragma unroll
      for (int h = 0; h < 2; ++h) {
        const unsigned short* q = bp + 16 * h;
        u2 b0 = *(const u2*)(q);
        u2 b1 = *(const u2*)(q + 4);
        u4 bv; bv.x = b0.x; bv.y = b0.y; bv.z = b1.x; bv.w = b1.y;
        short8 bfr = __builtin_bit_cast(short8, bv);
        oacc[nt] = __builtin_amdgcn_mfma_f32_32x32x16_bf16(wf[2 * p + h], bfr, oacc[nt], 0, 0, 0);
      }
    }
  }

  // ---- epilogue: D layout col = lane&31, row = (r&3) + 8*(r>>2) + 4*(l>>5) ----
  float* ob = out + (size_t)b * 16384;
#pragma unroll
  for (int nt = 0; nt < 4; ++nt) {
#pragma unroll
    for (int r = 0; r < 16; ++r) {
      int row = 32 * wave + (r & 3) + 8 * (r >> 2) + 4 * laneHi;
      int col = 32 * nt + lane31;
      ob[row * 128 + col] = oacc[nt][r];
    }
  }
}

extern "C" void kernel_launch(void* const* d_in, const int* in_sizes, int n_in,
                              void* d_out, int out_size, void* d_ws, size_t ws_size,
                              hipStream_t stream) {
  const float* X = (const float*)d_in[0];   // [2048,256,256] f32
  const float* W = (const float*)d_in[1];   // [256,128] f32
  unsigned short* Wf = (unsigned short*)d_ws;  // 64 KB bf16 fragment buffer

  prep_w<<<16, 256, 0, stream>>>(W, Wf);
  spd_kernel<<<2048, 256, 0, stream>>>(X, Wf, (float*)d_out);
}

// Round 2
// 713.028 us; speedup vs baseline: 1.0037x; 1.0037x over previous
//
#include <hip/hip_runtime.h>

// B=2048, N=256, M=128 ; out[b] = W^T X[b] W  (einsum "ji,bjk,kl->bil")
// v2: fused two-stage per batch, NO U round-trip through LDS.
//   wave w owns out cols [32w,32w+32): stage1 U_p[:,32w..] = X_p @ W[:,32w..]
//   stays in registers; D-layout -> B-operand layout via 4x shfl_xor(32).
//   stage2 A-operands (all 4 W col-blocks) JIT-loaded from L2-resident Wf.
// One barrier/iter (Xs staging only), distance-1 HBM prefetch.

typedef __attribute__((ext_vector_type(8))) short short8;
typedef __attribute__((ext_vector_type(16))) float floatx16;

struct __align__(8)  u2 { unsigned int x, y; };
struct __align__(16) u4 { unsigned int x, y, z, w; };

__device__ __forceinline__ unsigned short f2bf(float f) {
  unsigned int u = __builtin_bit_cast(unsigned int, f);
  u += 0x7FFFu + ((u >> 16) & 1u);          // RNE
  return (unsigned short)(u >> 16);
}

// pack two f32 -> one dword of 2 bf16 (RNE), via v_perm_b32
__device__ __forceinline__ unsigned bfpack(float x, float y) {
  unsigned ux = __builtin_bit_cast(unsigned, x);
  unsigned uy = __builtin_bit_cast(unsigned, y);
  ux += 0x7FFFu + ((ux >> 16) & 1u);
  uy += 0x7FFFu + ((uy >> 16) & 1u);
  return __builtin_amdgcn_perm(uy, ux, 0x07060302u);  // [uy.hi16 | ux.hi16]
}

// ---------------------------------------------------------------------------
// prep: W (256x128 f32 row-major) -> fragment-ordered bf16 in ws.
// Wf[(((blk*16)+t)*64 + l)*8 + j] = W[16t + 8*(l>>5) + j][32*blk + (l&31)]
// Serves stage1 B-operand (blk = wave col-block) AND stage2 A-operand
// (blk = out row-block) — identical lane layout for A and B operands.
// ---------------------------------------------------------------------------
__global__ void prep_w(const float* __restrict__ W, unsigned short* __restrict__ Wf) {
  int g = blockIdx.x * 256 + threadIdx.x;   // 4096 fragments of 8 elems
  int l = g & 63;
  int t = (g >> 6) & 15;
  int blk = g >> 10;
  int row0 = 16 * t + ((l >> 5) << 3);
  int col  = 32 * blk + (l & 31);
  unsigned short tmp[8];
#pragma unroll
  for (int j = 0; j < 8; ++j) tmp[j] = f2bf(W[(row0 + j) * 128 + col]);
  u4 v;
  v.x = (unsigned)tmp[0] | ((unsigned)tmp[1] << 16);
  v.y = (unsigned)tmp[2] | ((unsigned)tmp[3] << 16);
  v.z = (unsigned)tmp[4] | ((unsigned)tmp[5] << 16);
  v.w = (unsigned)tmp[6] | ((unsigned)tmp[7] << 16);
  *(u4*)(Wf + (size_t)g * 8) = v;
}

// ---------------------------------------------------------------------------
// main kernel: one batch per block, 256 threads (4 waves)
// ---------------------------------------------------------------------------
#define XS_STRIDE 264   // shorts; 528 B rows: 16B-aligned -> ds_read_b128 frags

__global__ __launch_bounds__(256, 2) void spd_kernel(
    const float* __restrict__ X,
    const unsigned short* __restrict__ Wf,
    float* __restrict__ out)
{
  __shared__ unsigned short Xs[2][32 * XS_STRIDE];   // 2 x 16.5 KB

  const int b      = blockIdx.x;
  const int tid    = threadIdx.x;
  const int wave   = tid >> 6;
  const int lane   = tid & 63;
  const int lane31 = lane & 31;
  const int laneHi = lane >> 5;   // 0/1

  // stage1 B fragments: own col-block, all 16 k-tiles (64 VGPRs, from L2)
  short8 wf[16];
  {
    const unsigned short* base = Wf + ((size_t)(wave * 16 * 64 + lane)) * 8;
#pragma unroll
    for (int t = 0; t < 16; ++t)
      wf[t] = *(const short8*)(base + t * 64 * 8);
  }

  const float* xb = X + (size_t)b * 65536;

  floatx16 oacc[4];
#pragma unroll
  for (int rb = 0; rb < 4; ++rb)
#pragma unroll
    for (int i = 0; i < 16; ++i) oacc[rb][i] = 0.0f;

  float4 xreg[8];
  auto load_tile = [&](int p) {            // 32x256 f32, perfectly coalesced
    const float* src = xb + p * 8192 + tid * 4;
#pragma unroll
    for (int q = 0; q < 8; ++q) xreg[q] = *(const float4*)(src + q * 1024);
  };
  auto store_tile = [&](int buf) {         // row 4q+wave, col 4*lane, bf16
#pragma unroll
    for (int q = 0; q < 8; ++q) {
      float4 v = xreg[q];
      u2 pk;
      pk.x = bfpack(v.x, v.y);
      pk.y = bfpack(v.z, v.w);
      *(u2*)&Xs[buf][(4 * q + wave) * XS_STRIDE + 4 * lane] = pk;
    }
  };

  load_tile(0);

  for (int p = 0; p < 8; ++p) {
    const int buf = p & 1;
    store_tile(buf);                       // waits on loads issued last iter

    // stage2 A-frags for this p: 8x dwordx4 from L2 (issue early, use late)
    short8 wfb[4][2];
#pragma unroll
    for (int rb = 0; rb < 4; ++rb)
#pragma unroll
      for (int h = 0; h < 2; ++h)
        wfb[rb][h] = *(const short8*)(
            Wf + ((size_t)((rb * 16 + 2 * p + h) * 64 + lane)) * 8);

    if (p < 7) load_tile(p + 1);           // HBM prefetch, distance 1
    __syncthreads();                       // Xs[buf] ready

    // ---- stage1: uacc = X_p @ W[:, 32*wave ..] ----
    floatx16 uacc;
#pragma unroll
    for (int i = 0; i < 16; ++i) uacc[i] = 0.0f;
    const unsigned short* xs = &Xs[buf][lane31 * XS_STRIDE + 8 * laneHi];
#pragma unroll
    for (int t = 0; t < 16; ++t) {
      short8 afr = __builtin_bit_cast(short8, *(const u4*)(xs + 16 * t));
      uacc = __builtin_amdgcn_mfma_f32_32x32x16_bf16(afr, wf[t], uacc, 0, 0, 0);
    }

    // ---- D-layout -> B-operand layout, in-register (no LDS, no barrier) ----
    // dword d[i] packs rows {0,1},{2,3},{8,9},{10,11},{16..},{18..},{24..},{26..} (+4 if laneHi)
    unsigned d[8];
#pragma unroll
    for (int i = 0; i < 8; ++i) d[i] = bfpack(uacc[2 * i], uacc[2 * i + 1]);
    unsigned e0 = __shfl_xor(laneHi ? d[0] : d[2], 32, 64);
    unsigned e1 = __shfl_xor(laneHi ? d[1] : d[3], 32, 64);
    unsigned e2 = __shfl_xor(laneHi ? d[4] : d[6], 32, 64);
    unsigned e3 = __shfl_xor(laneHi ? d[5] : d[7], 32, 64);
    u4 b0v, b1v;
    b0v.x = laneHi ? e0   : d[0];  b0v.y = laneHi ? e1   : d[1];
    b0v.z = laneHi ? d[2] : e0;    b0v.w = laneHi ? d[3] : e1;
    b1v.x = laneHi ? e2   : d[4];  b1v.y = laneHi ? e3   : d[5];
    b1v.z = laneHi ? d[6] : e2;    b1v.w = laneHi ? d[7] : e3;
    short8 bU0 = __builtin_bit_cast(short8, b0v);
    short8 bU1 = __builtin_bit_cast(short8, b1v);

    // ---- stage2: oacc[rb] += W_p^T(rb-block) @ U_p(own cols) ----
#pragma unroll
    for (int rb = 0; rb < 4; ++rb) {
      oacc[rb] = __builtin_amdgcn_mfma_f32_32x32x16_bf16(wfb[rb][0], bU0, oacc[rb], 0, 0, 0);
      oacc[rb] = __builtin_amdgcn_mfma_f32_32x32x16_bf16(wfb[rb][1], bU1, oacc[rb], 0, 0, 0);
    }
  }

  // ---- epilogue: D row=(r&3)+8*(r>>2)+4*laneHi, col=lane31 ----
  float* ob = out + (size_t)b * 16384 + 32 * wave + lane31;
#pragma unroll
  for (int rb = 0; rb < 4; ++rb)
#pragma unroll
    for (int r = 0; r < 16; ++r) {
      int row = 32 * rb + (r & 3) + 8 * (r >> 2) + 4 * laneHi;
      ob[row * 128] = oacc[rb][r];
    }
}

extern "C" void kernel_launch(void* const* d_in, const int* in_sizes, int n_in,
                              void* d_out, int out_size, void* d_ws, size_t ws_size,
                              hipStream_t stream) {
  const float* X = (const float*)d_in[0];      // [2048,256,256] f32
  const float* W = (const float*)d_in[1];      // [256,128] f32
  unsigned short* Wf = (unsigned short*)d_ws;  // 64 KB bf16 fragment buffer

  prep_w<<<16, 256, 0, stream>>>(W, Wf);
  spd_kernel<<<2048, 256, 0, stream>>>(X, Wf, (float*)d_out);
}